// Round 5
// baseline (445.046 us; speedup 1.0000x reference)
//
#include <hip/hip_runtime.h>

// B=8, T=2048, C=1024, H=1024 single-head causal self-attention.
// R5: (a) V-transpose folded into QKV epilogue (Vt written directly, ushort4
// per 4 consecutive t); (b) scores/PV block mapping reverted to R3 (R4's
// b=blk&7 XCD pin regressed ~30us); (c) nontemporal stores for S and out so
// the 64MB write streams stop evicting Q/K (S lines) from L2/L3.
//   1) cvt x -> bf16          2) cvt+transpose W* -> Wt [3072,1024]
//   3) QKV gemm -> Q,K,Vt     4) zero l
//   5) E = exp(scale*Q K^T) masked (nt store), l += rowsum
//   6) out = (E @ V) / l (nt store)

#define BM 128
#define BN 128
#define BK 32

typedef __attribute__((ext_vector_type(8))) __bf16 bf16x8;
typedef __attribute__((ext_vector_type(4))) float floatx4;

__device__ __forceinline__ unsigned short f2bf(float f) {
  unsigned int u = __float_as_uint(f);
  u += 0x7fffu + ((u >> 16) & 1u);   // round-to-nearest-even
  return (unsigned short)(u >> 16);
}
__device__ __forceinline__ float bf2f(unsigned short s) {
  return __uint_as_float(((unsigned int)s) << 16);
}

// global -> LDS direct DMA, 16B per lane. LDS dest is wave-uniform base + lane*16.
__device__ __forceinline__ void gload_lds16(const unsigned short* g, unsigned short* l) {
  __builtin_amdgcn_global_load_lds(
      (const __attribute__((address_space(1))) void*)g,
      (__attribute__((address_space(3))) void*)l,
      16, 0, 0);
}

// C = A (row-major [*,lda]) x Bt^T (Bt row-major [*,ldb]), 128x128 tile.
// 256 threads = 4 waves in 2x2 grid, each wave 64x64 via 4x4 mfma_16x16x32_bf16.
__device__ __forceinline__ void gemm_mainloop(
    const unsigned short* __restrict__ A, int lda,
    const unsigned short* __restrict__ Bt, int ldb,
    int m0, int n0, int kTiles,
    unsigned short* As, unsigned short* Bs,
    floatx4 (&acc)[4][4])
{
  const int tid  = threadIdx.x;
  const int wave = tid >> 6;
  const int lane = tid & 63;
  const int wr = wave >> 1;
  const int wc = wave & 1;

  // staging: 8KB tile = 8 chunks of 1KB; wave w stages chunks 2w, 2w+1 (A and B).
  const int c0 = wave * 2;
  const int c1 = c0 + 1;
  const int r0 = c0 * 16 + (lane >> 2);
  const int r1 = c1 * 16 + (lane >> 2);
  const int ck = (lane & 3) * 8;

  const unsigned short* pA0 = A  + (size_t)(m0 + r0) * lda + ck;
  const unsigned short* pA1 = A  + (size_t)(m0 + r1) * lda + ck;
  const unsigned short* pB0 = Bt + (size_t)(n0 + r0) * ldb + ck;
  const unsigned short* pB1 = Bt + (size_t)(n0 + r1) * ldb + ck;

  unsigned short* lA0 = As + c0 * 512;
  unsigned short* lA1 = As + c1 * 512;
  unsigned short* lB0 = Bs + c0 * 512;
  unsigned short* lB1 = Bs + c1 * 512;

  const int fr = lane & 15;          // fragment row (m for A, n for B)
  const int kq = (lane >> 4) * 8;    // k sub-chunk per quad

  for (int kt = 0; kt < kTiles; ++kt) {
    __syncthreads();                 // prior iter's readers done before overwrite
    gload_lds16(pA0, lA0);
    gload_lds16(pA1, lA1);
    gload_lds16(pB0, lB0);
    gload_lds16(pB1, lB1);
    pA0 += BK; pA1 += BK; pB0 += BK; pB1 += BK;
    __syncthreads();                 // vmcnt(0) drain: staging visible

    bf16x8 af[4], bg[4];
#pragma unroll
    for (int i = 0; i < 4; ++i)
      af[i] = *(const bf16x8*)(As + ((wr * 64 + i * 16 + fr) * BK + kq));
#pragma unroll
    for (int j = 0; j < 4; ++j)
      bg[j] = *(const bf16x8*)(Bs + ((wc * 64 + j * 16 + fr) * BK + kq));
#pragma unroll
    for (int i = 0; i < 4; ++i)
#pragma unroll
      for (int j = 0; j < 4; ++j)
        acc[i][j] = __builtin_amdgcn_mfma_f32_16x16x32_bf16(af[i], bg[j], acc[i][j], 0, 0, 0);
  }
}

#define ACC_INIT(acc)                         \
  do {                                        \
    floatx4 z_ = {0.f, 0.f, 0.f, 0.f};        \
    _Pragma("unroll")                         \
    for (int i_ = 0; i_ < 4; ++i_)            \
      _Pragma("unroll")                       \
      for (int j_ = 0; j_ < 4; ++j_)          \
        acc[i_][j_] = z_;                     \
  } while (0)

// ---------------- kernels ----------------

__global__ void cvt_x_kernel(const float* __restrict__ x, unsigned short* __restrict__ xb) {
  int idx = (blockIdx.x * 256 + threadIdx.x) * 4;
  float4 v = *(const float4*)(x + idx);
  ushort4 o;
  o.x = f2bf(v.x); o.y = f2bf(v.y); o.z = f2bf(v.z); o.w = f2bf(v.w);
  *(ushort4*)(xb + idx) = o;
}

// W: [1024 (k), 1024 (n)] f32  ->  Wt: [1024 (n), 1024 (k)] bf16
__global__ void cvt_w_kernel(const float* __restrict__ W, unsigned short* __restrict__ Wt) {
  __shared__ unsigned short tile[64][65];
  const int k0 = blockIdx.x * 64, n0 = blockIdx.y * 64;
  const int tid = threadIdx.x, tx = tid & 63, ty = tid >> 6;
#pragma unroll
  for (int r = 0; r < 64; r += 4)
    tile[r + ty][tx] = f2bf(W[(size_t)(k0 + r + ty) * 1024 + (n0 + tx)]);
  __syncthreads();
#pragma unroll
  for (int r = 0; r < 64; r += 4)
    Wt[(size_t)(n0 + r + ty) * 1024 + (k0 + tx)] = tile[tx][r + ty];
}

__global__ void zero_l_kernel(float* __restrict__ l) {
  l[blockIdx.x * 256 + threadIdx.x] = 0.f;
}

// [Q|K|V] = xb [16384,1024] @ Wt[3072,1024]^T.
// Q,K stored row-major [16384,1024]; V written TRANSPOSED to Vt[b][h][t].
__global__ __launch_bounds__(256) void gemm_qkv_kernel(
    const unsigned short* __restrict__ xb,
    const unsigned short* __restrict__ Wt,
    unsigned short* __restrict__ Q,
    unsigned short* __restrict__ K,
    unsigned short* __restrict__ Vt)
{
  __shared__ __align__(16) unsigned short As[BM * BK];
  __shared__ __align__(16) unsigned short Bs[BN * BK];
  floatx4 acc[4][4];
  ACC_INIT(acc);
  const int m0 = blockIdx.x * BM;
  const int n0 = blockIdx.y * BN;
  gemm_mainloop(xb, 1024, Wt, 1024, m0, n0, 1024 / BK, As, Bs, acc);

  const int tid = threadIdx.x, wave = tid >> 6, lane = tid & 63;
  const int wr = wave >> 1, wc = wave & 1;
  const int rb = m0 + wr * 64 + ((lane >> 4) << 2);   // global t-row
  if (n0 < 2048) {
    // Q or K: row-major
    unsigned short* D = (n0 < 1024) ? Q : K;
    const int cb = (n0 & 1023) + wc * 64 + (lane & 15);
#pragma unroll
    for (int i = 0; i < 4; ++i)
#pragma unroll
      for (int j = 0; j < 4; ++j)
#pragma unroll
        for (int r = 0; r < 4; ++r)
          D[(size_t)(rb + i * 16 + r) * 1024 + (cb + j * 16)] = f2bf(acc[i][j][r]);
  } else {
    // V: write transposed. lane's 4 acc regs = 4 consecutive t -> one ushort4.
    const int bb = m0 >> 11;               // batch (tile rows all in one batch)
    const int tl = rb & 2047;              // local t
    unsigned short* Vtb = Vt + (size_t)bb * 1024 * 2048;
    const int hb = (n0 - 2048) + wc * 64 + (lane & 15);
#pragma unroll
    for (int i = 0; i < 4; ++i)
#pragma unroll
      for (int j = 0; j < 4; ++j) {
        ushort4 o;
        o.x = f2bf(acc[i][j][0]); o.y = f2bf(acc[i][j][1]);
        o.z = f2bf(acc[i][j][2]); o.w = f2bf(acc[i][j][3]);
        *(ushort4*)(Vtb + (size_t)(hb + j * 16) * 2048 + (tl + i * 16)) = o;
      }
  }
}

// E[b] = exp(scale * Q[b] K[b]^T), causal; l[b,i] += row sums.
// R3 mapping: b = blk/136 (slow), t = blk%136 tri-tile.
__global__ __launch_bounds__(256) void gemm_scores_kernel(
    const unsigned short* __restrict__ Q,
    const unsigned short* __restrict__ K,
    unsigned short* __restrict__ S,
    float* __restrict__ lsum)
{
  const int b = blockIdx.x / 136;
  const int t = blockIdx.x % 136;
  int mi = (int)((sqrtf(8.f * (float)t + 1.f) - 1.f) * 0.5f);
  while ((mi + 1) * (mi + 2) / 2 <= t) ++mi;   // fp guard
  while (mi * (mi + 1) / 2 > t) --mi;
  const int ni = t - mi * (mi + 1) / 2;
  const int m0 = mi * BM;
  const int n0 = ni * BN;

  __shared__ __align__(16) unsigned short As[BM * BK];
  __shared__ __align__(16) unsigned short Bs[BN * BK];
  floatx4 acc[4][4];
  ACC_INIT(acc);
  const unsigned short* Qb = Q + (size_t)b * 2048 * 1024;
  const unsigned short* Kb = K + (size_t)b * 2048 * 1024;
  gemm_mainloop(Qb, 1024, Kb, 1024, m0, n0, 1024 / BK, As, Bs, acc);

  unsigned short* Sb = S + (size_t)b * 2048 * 2048;
  float* lb = lsum + b * 2048;
  const int tid = threadIdx.x, wave = tid >> 6, lane = tid & 63;
  const int wr = wave >> 1, wc = wave & 1;
  const int rb = m0 + wr * 64 + ((lane >> 4) << 2);
  const int cb = n0 + wc * 64 + (lane & 15);

  float rsum[4][4];
#pragma unroll
  for (int i = 0; i < 4; ++i)
#pragma unroll
    for (int r = 0; r < 4; ++r)
      rsum[i][r] = 0.f;

#pragma unroll
  for (int i = 0; i < 4; ++i)
#pragma unroll
    for (int j = 0; j < 4; ++j)
#pragma unroll
      for (int r = 0; r < 4; ++r) {
        const int tq = rb + i * 16 + r;
        const int tk = cb + j * 16;
        float e = 0.f;
        if (tk <= tq) e = __expf(acc[i][j][r] * 0.03125f);  // scale = 1/32
        const unsigned short h = f2bf(e);
        __builtin_nontemporal_store(h, &Sb[(size_t)tq * 2048 + tk]);
        rsum[i][r] += bf2f(h);   // l consistent with stored bf16 E
      }

  // reduce across the 16 lanes of each quad (same rows, different cols)
#pragma unroll
  for (int off = 1; off < 16; off <<= 1)
#pragma unroll
    for (int i = 0; i < 4; ++i)
#pragma unroll
      for (int r = 0; r < 4; ++r)
        rsum[i][r] += __shfl_xor(rsum[i][r], off, 64);

  if ((lane & 15) == 0) {
#pragma unroll
    for (int i = 0; i < 4; ++i)
#pragma unroll
      for (int r = 0; r < 4; ++r)
        atomicAdd(&lb[rb + i * 16 + r], rsum[i][r]);
  }
}

// out[b] = (E[b] @ V[b]) / l. R3 LPT mapping: heavy mi first, b fast.
__global__ __launch_bounds__(256) void gemm_pv_kernel(
    const unsigned short* __restrict__ S,
    const unsigned short* __restrict__ Vt,
    const float* __restrict__ lsum,
    float* __restrict__ out)
{
  const int mi = 15 - (int)(blockIdx.x >> 6);  // 15,15,...,0 (heavy first)
  const int rest = blockIdx.x & 63;
  const int b = rest >> 3;
  const int ni = rest & 7;
  const int m0 = mi * BM;
  const int n0 = ni * BN;

  __shared__ __align__(16) unsigned short As[BM * BK];
  __shared__ __align__(16) unsigned short Bs[BN * BK];
  floatx4 acc[4][4];
  ACC_INIT(acc);
  const unsigned short* Pb = S  + (size_t)b * 2048 * 2048;   // lda 2048
  const unsigned short* Vb = Vt + (size_t)b * 1024 * 2048;   // ldb 2048
  const int kTiles = m0 / BK + BM / BK;                      // tk <= m0+127
  gemm_mainloop(Pb, 2048, Vb, 2048, m0, n0, kTiles, As, Bs, acc);

  float* Ob = out + (size_t)b * 2048 * 1024;
  const float* lb = lsum + b * 2048;
  const int tid = threadIdx.x, wave = tid >> 6, lane = tid & 63;
  const int wr = wave >> 1, wc = wave & 1;
  const int rb = m0 + wr * 64 + ((lane >> 4) << 2);
  const int cb = n0 + wc * 64 + (lane & 15);

  float inv[4][4];
#pragma unroll
  for (int i = 0; i < 4; ++i)
#pragma unroll
    for (int r = 0; r < 4; ++r)
      inv[i][r] = 1.0f / lb[rb + i * 16 + r];

#pragma unroll
  for (int i = 0; i < 4; ++i)
#pragma unroll
    for (int j = 0; j < 4; ++j)
#pragma unroll
      for (int r = 0; r < 4; ++r)
        __builtin_nontemporal_store(acc[i][j][r] * inv[i][r],
            &Ob[(size_t)(rb + i * 16 + r) * 1024 + (cb + j * 16)]);
}

// ---------------- launcher ----------------

extern "C" void kernel_launch(void* const* d_in, const int* in_sizes, int n_in,
                              void* d_out, int out_size, void* d_ws, size_t ws_size,
                              hipStream_t stream) {
  const float* x  = (const float*)d_in[0];
  const float* Wq = (const float*)d_in[1];
  const float* Wk = (const float*)d_in[2];
  const float* Wv = (const float*)d_in[3];
  float* out = (float*)d_out;

  char* ws = (char*)d_ws;
  unsigned short* xb  = (unsigned short*)(ws);                     //  33,554,432 B
  unsigned short* Wt  = (unsigned short*)(ws + 33554432ull);       //   6,291,456 B
  unsigned short* Q   = (unsigned short*)(ws + 39845888ull);       //  33,554,432 B
  unsigned short* K   = (unsigned short*)(ws + 73400320ull);       //  33,554,432 B
  unsigned short* Vt  = (unsigned short*)(ws + 140509184ull);      //  33,554,432 B
  unsigned short* S   = (unsigned short*)(ws + 174063616ull);      //  67,108,864 B
  float*          l   = (float*)ws;   // aliases xb: dead after QKV gemm
  // total ws use: 241,172,480 B

  cvt_x_kernel<<<16384, 256, 0, stream>>>(x, xb);
  dim3 gw(16, 16);
  cvt_w_kernel<<<gw, 256, 0, stream>>>(Wq, Wt);
  cvt_w_kernel<<<gw, 256, 0, stream>>>(Wk, Wt + 1024 * 1024);
  cvt_w_kernel<<<gw, 256, 0, stream>>>(Wv, Wt + 2 * 1024 * 1024);

  gemm_qkv_kernel<<<dim3(128, 24), 256, 0, stream>>>(xb, Wt, Q, K, Vt);

  zero_l_kernel<<<64, 256, 0, stream>>>(l);   // after QKV: l aliases xb
  gemm_scores_kernel<<<8 * 136, 256, 0, stream>>>(Q, K, S, l);
  gemm_pv_kernel<<<1024, 256, 0, stream>>>(S, Vt, l, out);
}